// Round 10
// baseline (43.745 us; speedup 1.0000x reference)
//
#include <hip/hip_runtime.h>
#include <math.h>

// Problem constants: B=16, N=M=4096, K=64.
// DIAGNOSTIC ROUND: identical to R9 but the jt loop executes TWICE
// (idempotent min work, __syncthreads between reps blocks CSE) so the
// chamfer kernel's duration doubles and surfaces in the rocprof top-5
// above the harness's 38-39us poison fills, giving real PMC visibility.
#define BB 16
#define NN 4096
#define MM 4096
#define NSLICE 2
#define SLICE_COLS 2048               // cols staged per block
#define NJT (SLICE_COLS / 64)         // 32
#define ROWS_PER_BLOCK 256            // 4 waves x 64 rows
#define NCHAMFER 512                  // 16 row-tiles * 2 col-slices * 16 b
#define EPW 2176                      // row-epilogue floats per wave (32*68)
#define WSCOL_OFF (BB * NSLICE * NN)  // 131072

typedef __attribute__((ext_vector_type(8))) short bf16x8;
typedef __attribute__((ext_vector_type(16))) float f32x16;

static __device__ inline unsigned short f2bf(float f) {
    unsigned int u = __float_as_uint(f);
    return (unsigned short)((u + 0x7FFFu + ((u >> 16) & 1u)) >> 16);  // RNE
}
static __device__ inline bf16x8 bzero() {
    bf16x8 z;
    #pragma unroll
    for (int i = 0; i < 8; ++i) z[i] = 0;
    return z;
}
static __device__ inline f32x16 fzero16() {
    f32x16 z;
    #pragma unroll
    for (int i = 0; i < 16; ++i) z[i] = 0.f;
    return z;
}

#define MFMA32(Af, Bf, Cf) __builtin_amdgcn_mfma_f32_32x32x16_bf16(Af, Bf, Cf, 0, 0, 0)

__global__ __launch_bounds__(256, 2) void chamfer_min_kernel(
    const float* __restrict__ pred, const float* __restrict__ gt,
    const float* __restrict__ trans, float* __restrict__ ws,
    float* __restrict__ out)
{
    const int bx  = blockIdx.x;
    const int tid = threadIdx.x;

    if (bx >= NCHAMFER) {
        // ------------------------- regularizer -------------------------
        if (tid < 64) {
            const int b = bx - NCHAMFER;
            const int lane = tid;
            const int hi = lane >> 5, li = lane & 31;
            const float* T = trans + (size_t)b * 64 * 64;
            bf16x8 frag[2][4];
            #pragma unroll
            for (int h = 0; h < 2; ++h)
                #pragma unroll
                for (int s = 0; s < 4; ++s) {
                    const float* rp = T + (size_t)(h * 32 + li) * 64 + s * 16 + hi * 8;
                    const float4 u0 = *(const float4*)rp;
                    const float4 u1 = *(const float4*)(rp + 4);
                    bf16x8 fr;
                    fr[0] = (short)f2bf(u0.x); fr[1] = (short)f2bf(u0.y);
                    fr[2] = (short)f2bf(u0.z); fr[3] = (short)f2bf(u0.w);
                    fr[4] = (short)f2bf(u1.x); fr[5] = (short)f2bf(u1.y);
                    fr[6] = (short)f2bf(u1.z); fr[7] = (short)f2bf(u1.w);
                    frag[h][s] = fr;
                }
            float fsum = 0.f;
            #pragma unroll
            for (int fi = 0; fi < 2; ++fi)
                #pragma unroll
                for (int fj = 0; fj < 2; ++fj) {
                    f32x16 a = fzero16();
                    #pragma unroll
                    for (int s = 0; s < 4; ++s)
                        a = MFMA32(frag[fi][s], frag[fj][s], a);
                    #pragma unroll
                    for (int r = 0; r < 16; ++r) {
                        const int row = fi * 32 + (r & 3) + 8 * (r >> 2) + 4 * hi;
                        const int col = fj * 32 + li;
                        const float d = a[r] - ((row == col) ? 1.0f : 0.0f);
                        fsum = fmaf(d, d, fsum);
                    }
                }
            #pragma unroll
            for (int off = 32; off > 0; off >>= 1)
                fsum += __shfl_down(fsum, off, 64);
            if (lane == 0)
                atomicAdd(out, (0.1f / (float)BB) * sqrtf(fsum));
        }
        return;
    }

    // --------------------------- chamfer -----------------------------
    __shared__ __align__(16) float smem[8704];       // stage 32KB | row-epi 34.8KB
    __shared__ unsigned int colmin[SLICE_COLS];      // 8KB block-wide col mins

    const int lane = tid & 63;
    const int w    = tid >> 6;
    const int li   = lane & 31;
    const int hi   = lane >> 5;
    const int tile   = bx & 15;
    const int mslice = (bx >> 4) & 1;
    const int b      = bx >> 5;
    const float* rb = pred + (size_t)b * NN * 3;
    const float* cb = gt + ((size_t)b * MM + (size_t)mslice * SLICE_COLS) * 3;

    const int rbase = tile * ROWS_PER_BLOCK + w * 64;
    bf16x8 A0 = bzero(), A1 = bzero();
    if (lane < 32) {
        #pragma unroll
        for (int f = 0; f < 2; ++f) {
            const float* rp = rb + (size_t)(rbase + f * 32 + li) * 3;
            const float px = rp[0], py = rp[1], pz = rp[2];
            const float p2 = px * px + py * py + pz * pz;
            bf16x8 fr = bzero();
            fr[0] = (short)f2bf(-2.f * px);
            fr[1] = (short)f2bf(-2.f * py);
            fr[2] = (short)f2bf(-2.f * pz);
            fr[3] = (short)f2bf(p2);
            fr[4] = (short)0x3F80;          // 1.0
            if (f == 0) A0 = fr; else A1 = fr;
        }
    }

    uint4* sB = (uint4*)smem;
    #pragma unroll
    for (int i = 0; i < SLICE_COLS / 512; ++i) {
        const int c0 = i * 512 + 2 * tid;
        const float2* sp = (const float2*)(cb + (size_t)c0 * 3);
        const float2 v0 = sp[0], v1 = sp[1], v2 = sp[2];
        const float t2a = v0.x * v0.x + v0.y * v0.y + v1.x * v1.x;
        const float t2b = v1.y * v1.y + v2.x * v2.x + v2.y * v2.y;
        uint4 pa, pb;
        pa.x = (unsigned)f2bf(v0.x) | ((unsigned)f2bf(v0.y) << 16);
        pa.y = (unsigned)f2bf(v1.x) | (0x3F80u << 16);
        pa.z = (unsigned)f2bf(t2a);
        pa.w = 0u;
        pb.x = (unsigned)f2bf(v1.y) | ((unsigned)f2bf(v2.x) << 16);
        pb.y = (unsigned)f2bf(v2.y) | (0x3F80u << 16);
        pb.z = (unsigned)f2bf(t2b);
        pb.w = 0u;
        sB[c0]     = pa;
        sB[c0 + 1] = pb;
    }
    #pragma unroll
    for (int i = 0; i < SLICE_COLS / 256; ++i)
        colmin[i * 256 + tid] = 0x7F7FFFFFu;         // FLT_MAX bits
    __syncthreads();

    float mv0[16], mv1[16];
    #pragma unroll
    for (int r = 0; r < 16; ++r) { mv0[r] = 3.4e38f; mv1[r] = 3.4e38f; }

    const f32x16 Z = fzero16();
    const bf16x8* sBf = (const bf16x8*)smem;

    // DIAGNOSTIC: run the identical (idempotent) jt loop twice. The
    // __syncthreads between reps is an LDS memory barrier, so the compiler
    // must re-execute the second pass. Output is bitwise identical.
    for (int rep = 0; rep < 2; ++rep) {
        #pragma unroll 2
        for (int jt = 0; jt < NJT; ++jt) {
            const bf16x8 c1 = sBf[jt * 64 + li];
            const bf16x8 c2 = sBf[jt * 64 + 32 + li];
            f32x16 a0 = MFMA32(A0, c1, Z);
            f32x16 a1 = MFMA32(A0, c2, Z);
            f32x16 a2 = MFMA32(A1, c1, Z);
            f32x16 a3 = MFMA32(A1, c2, Z);
            #pragma unroll
            for (int r = 0; r < 16; ++r)
                mv0[r] = fminf(fminf(a0[r], a1[r]), mv0[r]);
            #pragma unroll
            for (int r = 0; r < 16; ++r)
                mv1[r] = fminf(fminf(a2[r], a3[r]), mv1[r]);
            float tA = fminf(a0[0], a0[1]);
            #pragma unroll
            for (int i = 1; i < 8; ++i) tA = fminf(fminf(a0[2*i], a0[2*i+1]), tA);
            #pragma unroll
            for (int i = 0; i < 8; ++i) tA = fminf(fminf(a2[2*i], a2[2*i+1]), tA);
            float tB = fminf(a1[0], a1[1]);
            #pragma unroll
            for (int i = 1; i < 8; ++i) tB = fminf(fminf(a1[2*i], a1[2*i+1]), tB);
            #pragma unroll
            for (int i = 0; i < 8; ++i) tB = fminf(fminf(a3[2*i], a3[2*i+1]), tB);
            atomicMin(&colmin[jt * 64 + li],      __float_as_uint(tA + 1.0f));
            atomicMin(&colmin[jt * 64 + 32 + li], __float_as_uint(tB + 1.0f));
        }
        __syncthreads();                             // compiler barrier between reps
    }

    // Row epilogue: transpose partial mins via LDS [li][row], stride 68.
    {
        float* wb = smem + w * EPW + li * 68;
        #pragma unroll
        for (int q = 0; q < 4; ++q) {
            const int rl = q * 8 + hi * 4;
            *(float4*)&wb[rl]      = make_float4(mv0[4*q], mv0[4*q+1], mv0[4*q+2], mv0[4*q+3]);
            *(float4*)&wb[rl + 32] = make_float4(mv1[4*q], mv1[4*q+1], mv1[4*q+2], mv1[4*q+3]);
        }
    }
    __syncthreads();

    {
        const int wsrc = tid >> 6, rl = tid & 63;
        const float* rb2 = smem + wsrc * EPW + rl;
        float m = 3.4e38f;
        #pragma unroll
        for (int c = 0; c < 32; ++c) m = fminf(m, rb2[c * 68]);
        ws[((size_t)b * NSLICE + mslice) * NN + tile * ROWS_PER_BLOCK + tid] = m;
    }
    {
        float* wc = ws + WSCOL_OFF
                  + (((size_t)b * 16 + tile) * NSLICE + mslice) * SLICE_COLS;
        #pragma unroll
        for (int i = 0; i < SLICE_COLS / 256; ++i) {
            const int c = i * 256 + tid;
            wc[c] = __uint_as_float(colmin[c]) - 1.0f;
        }
    }
}

__global__ __launch_bounds__(256) void chamfer_finish_kernel(
    const float* __restrict__ ws, float* __restrict__ out)
{
    const int tid = threadIdx.x;
    const int g = blockIdx.x * 256 + tid;           // 0 .. 131071
    float v;
    if (g < BB * NN) {                              // pred rows
        const int b = g >> 12, n = g & (NN - 1);
        const float* p = ws + ((size_t)b * NSLICE) * NN + n;
        v = fminf(p[0], p[NN]);
    } else {                                        // gt cols
        const int h = g - BB * NN;
        const int b = h >> 12, m = h & (MM - 1);
        const int s = m >> 11, c = m & (SLICE_COLS - 1);
        const float* p = ws + WSCOL_OFF + (((size_t)b * 16) * NSLICE + s) * SLICE_COLS + c;
        v = p[0];
        #pragma unroll
        for (int t = 1; t < 16; ++t)
            v = fminf(v, p[(size_t)t * NSLICE * SLICE_COLS]);
    }
    float d = sqrtf(fmaxf(v, 0.0f));
    #pragma unroll
    for (int off = 32; off > 0; off >>= 1)
        d += __shfl_down(d, off, 64);
    __shared__ float ssum[4];
    if ((tid & 63) == 0) ssum[tid >> 6] = d;
    __syncthreads();
    if (tid == 0) {
        const float s = ssum[0] + ssum[1] + ssum[2] + ssum[3];
        atomicAdd(out, s * (1.0f / ((float)BB * (float)NN)));
    }
}

extern "C" void kernel_launch(void* const* d_in, const int* in_sizes, int n_in,
                              void* d_out, int out_size, void* d_ws, size_t ws_size,
                              hipStream_t stream)
{
    const float* pred  = (const float*)d_in[0];
    const float* gt    = (const float*)d_in[1];
    const float* trans = (const float*)d_in[2];
    float* out = (float*)d_out;
    float* ws = (float*)d_ws;

    hipMemsetAsync(out, 0, sizeof(float), stream);
    chamfer_min_kernel<<<dim3(NCHAMFER + BB), dim3(256), 0, stream>>>(
        pred, gt, trans, ws, out);
    chamfer_finish_kernel<<<dim3((2 * BB * NN) / 256), dim3(256), 0, stream>>>(
        ws, out);
}

// Round 11
// 29.241 us; speedup vs baseline: 1.4960x; 1.4960x over previous
//
#include <hip/hip_runtime.h>
#include <math.h>

// Problem constants: B=16, N=M=4096, K=64.
#define BB 16
#define NN 4096
#define MM 4096
#define NSLICE 2
#define SLICE_COLS 2048               // cols staged per block
#define NJT (SLICE_COLS / 64)         // 32
#define ROWS_PER_BLOCK 256            // 4 waves x 64 rows
#define NCHAMFER 512                  // 16 row-tiles * 2 col-slices * 16 b
#define EPW 2176                      // row-epilogue floats per wave (32*68)
#define WSCOL_OFF (BB * NSLICE * NN)  // 131072

typedef __attribute__((ext_vector_type(8))) short bf16x8;
typedef __attribute__((ext_vector_type(16))) float f32x16;

static __device__ inline unsigned short f2bf(float f) {
    unsigned int u = __float_as_uint(f);
    return (unsigned short)((u + 0x7FFFu + ((u >> 16) & 1u)) >> 16);  // RNE
}
static __device__ inline bf16x8 bzero() {
    bf16x8 z;
    #pragma unroll
    for (int i = 0; i < 8; ++i) z[i] = 0;
    return z;
}
static __device__ inline f32x16 fzero16() {
    f32x16 z;
    #pragma unroll
    for (int i = 0; i < 16; ++i) z[i] = 0.f;
    return z;
}
static __device__ inline float min3f(float a, float b, float c) {
    return fminf(fminf(a, b), c);     // clang fuses to v_min3_f32
}
// min over 32 values (two f32x16) via min3 tree: 17 ops, depth ~4.
static __device__ inline float colmin32(const f32x16 x, const f32x16 y) {
    float e[32];
    #pragma unroll
    for (int i = 0; i < 16; ++i) { e[i] = x[i]; e[16 + i] = y[i]; }
    float p[11];
    #pragma unroll
    for (int i = 0; i < 10; ++i) p[i] = min3f(e[3*i], e[3*i+1], e[3*i+2]);
    p[10] = fminf(e[30], e[31]);
    const float q0 = min3f(p[0], p[1], p[2]);
    const float q1 = min3f(p[3], p[4], p[5]);
    const float q2 = min3f(p[6], p[7], p[8]);
    const float q3 = fminf(p[9], p[10]);
    return fminf(min3f(q0, q1, q2), q3);
}

#define MFMA32(Af, Bf, Cf) __builtin_amdgcn_mfma_f32_32x32x16_bf16(Af, Bf, Cf, 0, 0, 0)

// ---------------------------------------------------------------------------
// Chamfer pass: ONE distance matrix, BOTH reductions (R9 structure).
// d2 = dot_K5([-2p,p2,1],[t,1,t2]) in a single 32x32x16 MFMA. Rows (pred)
// reduce in registers; cols (gt) via LDS atomicMin (+1 bias, bits monotone).
// Grid: EXACTLY 512 blocks (2/CU, one residency round; reg moved to finish).
// Block 0 zeroes out (only finish touches it afterwards; kernel boundary
// orders the store before finish's atomics). No memset dispatch.
// ---------------------------------------------------------------------------
__global__ __launch_bounds__(256, 2) void chamfer_min_kernel(
    const float* __restrict__ pred, const float* __restrict__ gt,
    float* __restrict__ ws, float* __restrict__ out)
{
    const int bx  = blockIdx.x;
    const int tid = threadIdx.x;
    if (bx == 0 && tid == 0) *out = 0.0f;

    __shared__ __align__(16) float smem[8704];       // stage 32KB | row-epi 34.8KB
    __shared__ unsigned int colmin[SLICE_COLS];      // 8KB block-wide col mins

    const int lane = tid & 63;
    const int w    = tid >> 6;
    const int li   = lane & 31;
    const int hi   = lane >> 5;
    const int tile   = bx & 15;
    const int mslice = (bx >> 4) & 1;
    const int b      = bx >> 5;
    const float* rb = pred + (size_t)b * NN * 3;
    const float* cb = gt + ((size_t)b * MM + (size_t)mslice * SLICE_COLS) * 3;

    // A-frags (pred rows): lanes 0-31 carry k=0..7 (k0..4 used); lanes 32-63 zero.
    const int rbase = tile * ROWS_PER_BLOCK + w * 64;
    bf16x8 A0 = bzero(), A1 = bzero();
    if (lane < 32) {
        #pragma unroll
        for (int f = 0; f < 2; ++f) {
            const float* rp = rb + (size_t)(rbase + f * 32 + li) * 3;
            const float px = rp[0], py = rp[1], pz = rp[2];
            const float p2 = px * px + py * py + pz * pz;
            bf16x8 fr = bzero();
            fr[0] = (short)f2bf(-2.f * px);
            fr[1] = (short)f2bf(-2.f * py);
            fr[2] = (short)f2bf(-2.f * pz);
            fr[3] = (short)f2bf(p2);
            fr[4] = (short)0x3F80;          // 1.0
            if (f == 0) A0 = fr; else A1 = fr;
        }
    }

    // Stage gt slice: packed bf16x8 per col = (t,1,t2,0,0,0); init colmin.
    uint4* sB = (uint4*)smem;
    #pragma unroll
    for (int i = 0; i < SLICE_COLS / 512; ++i) {
        const int c0 = i * 512 + 2 * tid;
        const float2* sp = (const float2*)(cb + (size_t)c0 * 3);
        const float2 v0 = sp[0], v1 = sp[1], v2 = sp[2];
        const float t2a = v0.x * v0.x + v0.y * v0.y + v1.x * v1.x;
        const float t2b = v1.y * v1.y + v2.x * v2.x + v2.y * v2.y;
        uint4 pa, pb;
        pa.x = (unsigned)f2bf(v0.x) | ((unsigned)f2bf(v0.y) << 16);
        pa.y = (unsigned)f2bf(v1.x) | (0x3F80u << 16);
        pa.z = (unsigned)f2bf(t2a);
        pa.w = 0u;
        pb.x = (unsigned)f2bf(v1.y) | ((unsigned)f2bf(v2.x) << 16);
        pb.y = (unsigned)f2bf(v2.y) | (0x3F80u << 16);
        pb.z = (unsigned)f2bf(t2b);
        pb.w = 0u;
        sB[c0]     = pa;
        sB[c0 + 1] = pb;
    }
    #pragma unroll
    for (int i = 0; i < SLICE_COLS / 256; ++i)
        colmin[i * 256 + tid] = 0x7F7FFFFFu;         // FLT_MAX bits
    __syncthreads();

    float mv0[16], mv1[16];
    #pragma unroll
    for (int r = 0; r < 16; ++r) { mv0[r] = 3.4e38f; mv1[r] = 3.4e38f; }

    const f32x16 Z = fzero16();
    const bf16x8* sBf = (const bf16x8*)smem;

    #pragma unroll 2
    for (int jt = 0; jt < NJT; ++jt) {
        const bf16x8 c1 = sBf[jt * 64 + li];         // lanes>=32 dup (A=0 there)
        const bf16x8 c2 = sBf[jt * 64 + 32 + li];
        f32x16 a0 = MFMA32(A0, c1, Z);
        f32x16 a1 = MFMA32(A0, c2, Z);
        f32x16 a2 = MFMA32(A1, c1, Z);
        f32x16 a3 = MFMA32(A1, c2, Z);
        // row mins (pred side): min3 folds both col-groups per op
        #pragma unroll
        for (int r = 0; r < 16; ++r)
            mv0[r] = min3f(a0[r], a1[r], mv0[r]);
        #pragma unroll
        for (int r = 0; r < 16; ++r)
            mv1[r] = min3f(a2[r], a3[r], mv1[r]);
        // col mins (gt side): min3 trees (17 ops per col vs 31 fminf)
        atomicMin(&colmin[jt * 64 + li],      __float_as_uint(colmin32(a0, a2) + 1.0f));
        atomicMin(&colmin[jt * 64 + 32 + li], __float_as_uint(colmin32(a1, a3) + 1.0f));
    }

    // Row epilogue: transpose partial mins via LDS [li][row], stride 68.
    __syncthreads();                                  // colmin final, stage free
    {
        float* wb = smem + w * EPW + li * 68;
        #pragma unroll
        for (int q = 0; q < 4; ++q) {
            const int rl = q * 8 + hi * 4;
            *(float4*)&wb[rl]      = make_float4(mv0[4*q], mv0[4*q+1], mv0[4*q+2], mv0[4*q+3]);
            *(float4*)&wb[rl + 32] = make_float4(mv1[4*q], mv1[4*q+1], mv1[4*q+2], mv1[4*q+3]);
        }
    }
    __syncthreads();

    // rows: 256 rows, 256 threads; plain store (unique writer per (b,slice,row))
    {
        const int wsrc = tid >> 6, rl = tid & 63;
        const float* rb2 = smem + wsrc * EPW + rl;
        float m = 3.4e38f;
        #pragma unroll
        for (int c = 0; c < 32; c += 2) m = min3f(rb2[c * 68], rb2[(c + 1) * 68], m);
        ws[((size_t)b * NSLICE + mslice) * NN + tile * ROWS_PER_BLOCK + tid] = m;
    }
    // cols: 2048 cols, 8 per thread; decode bias; unique writer per (b,tile,slice,col)
    {
        float* wc = ws + WSCOL_OFF
                  + (((size_t)b * 16 + tile) * NSLICE + mslice) * SLICE_COLS;
        #pragma unroll
        for (int i = 0; i < SLICE_COLS / 256; ++i) {
            const int c = i * 256 + tid;
            wc[c] = __uint_as_float(colmin[c]) - 1.0f;
        }
    }
}

// ---------------------------------------------------------------------------
// Finish (+reg): blocks [0,512): rows min over 2 slices / cols min over 16
// tiles, sqrt, mean-reduce, atomicAdd. Blocks [512,528): regularizer via MFMA.
// ---------------------------------------------------------------------------
__global__ __launch_bounds__(256) void finish_reg_kernel(
    const float* __restrict__ ws, const float* __restrict__ trans,
    float* __restrict__ out)
{
    const int bx  = blockIdx.x;
    const int tid = threadIdx.x;

    if (bx >= (2 * BB * NN) / 256) {
        // ------------------------- regularizer -------------------------
        if (tid < 64) {
            const int b = bx - (2 * BB * NN) / 256;
            const int lane = tid;
            const int hi = lane >> 5, li = lane & 31;
            const float* T = trans + (size_t)b * 64 * 64;
            bf16x8 frag[2][4];
            #pragma unroll
            for (int h = 0; h < 2; ++h)
                #pragma unroll
                for (int s = 0; s < 4; ++s) {
                    const float* rp = T + (size_t)(h * 32 + li) * 64 + s * 16 + hi * 8;
                    const float4 u0 = *(const float4*)rp;
                    const float4 u1 = *(const float4*)(rp + 4);
                    bf16x8 fr;
                    fr[0] = (short)f2bf(u0.x); fr[1] = (short)f2bf(u0.y);
                    fr[2] = (short)f2bf(u0.z); fr[3] = (short)f2bf(u0.w);
                    fr[4] = (short)f2bf(u1.x); fr[5] = (short)f2bf(u1.y);
                    fr[6] = (short)f2bf(u1.z); fr[7] = (short)f2bf(u1.w);
                    frag[h][s] = fr;
                }
            float fsum = 0.f;
            #pragma unroll
            for (int fi = 0; fi < 2; ++fi)
                #pragma unroll
                for (int fj = 0; fj < 2; ++fj) {
                    f32x16 a = fzero16();
                    #pragma unroll
                    for (int s = 0; s < 4; ++s)
                        a = MFMA32(frag[fi][s], frag[fj][s], a);
                    #pragma unroll
                    for (int r = 0; r < 16; ++r) {
                        const int row = fi * 32 + (r & 3) + 8 * (r >> 2) + 4 * hi;
                        const int col = fj * 32 + li;
                        const float d = a[r] - ((row == col) ? 1.0f : 0.0f);
                        fsum = fmaf(d, d, fsum);
                    }
                }
            #pragma unroll
            for (int off = 32; off > 0; off >>= 1)
                fsum += __shfl_down(fsum, off, 64);
            if (lane == 0)
                atomicAdd(out, (0.1f / (float)BB) * sqrtf(fsum));
        }
        return;
    }

    const int g = bx * 256 + tid;                   // 0 .. 131071
    float v;
    if (g < BB * NN) {                              // pred rows
        const int b = g >> 12, n = g & (NN - 1);
        const float* p = ws + ((size_t)b * NSLICE) * NN + n;
        v = fminf(p[0], p[NN]);
    } else {                                        // gt cols
        const int h = g - BB * NN;
        const int b = h >> 12, m = h & (MM - 1);
        const int s = m >> 11, c = m & (SLICE_COLS - 1);
        const float* p = ws + WSCOL_OFF + (((size_t)b * 16) * NSLICE + s) * SLICE_COLS + c;
        v = p[0];
        #pragma unroll
        for (int t = 1; t < 15; t += 2)
            v = min3f(p[(size_t)t * NSLICE * SLICE_COLS],
                      p[(size_t)(t + 1) * NSLICE * SLICE_COLS], v);
    }
    float d = sqrtf(fmaxf(v, 0.0f));
    #pragma unroll
    for (int off = 32; off > 0; off >>= 1)
        d += __shfl_down(d, off, 64);
    __shared__ float ssum[4];
    if ((tid & 63) == 0) ssum[tid >> 6] = d;
    __syncthreads();
    if (tid == 0) {
        const float s = ssum[0] + ssum[1] + ssum[2] + ssum[3];
        atomicAdd(out, s * (1.0f / ((float)BB * (float)NN)));
    }
}

extern "C" void kernel_launch(void* const* d_in, const int* in_sizes, int n_in,
                              void* d_out, int out_size, void* d_ws, size_t ws_size,
                              hipStream_t stream)
{
    const float* pred  = (const float*)d_in[0];
    const float* gt    = (const float*)d_in[1];
    const float* trans = (const float*)d_in[2];
    float* out = (float*)d_out;
    float* ws = (float*)d_ws;

    chamfer_min_kernel<<<dim3(NCHAMFER), dim3(256), 0, stream>>>(pred, gt, ws, out);
    finish_reg_kernel<<<dim3((2 * BB * NN) / 256 + BB), dim3(256), 0, stream>>>(
        ws, trans, out);
}

// Round 12
// 27.925 us; speedup vs baseline: 1.5665x; 1.0471x over previous
//
#include <hip/hip_runtime.h>
#include <math.h>

// Problem constants: B=16, N=M=4096, K=64.
#define BB 16
#define NN 4096
#define MM 4096
#define NSLICE 2
#define SLICE_COLS 2048               // cols staged per block
#define NJT (SLICE_COLS / 64)         // 32
#define ROWS_PER_BLOCK 256            // 4 waves x 64 rows
#define NCHAMFER 512                  // 16 row-tiles * 2 col-slices * 16 b
#define EPW 2176                      // row-epilogue floats per wave (32*68)
#define CSTRIDE 2080                  // u16 per colw plane (2048 + 32 pad)
#define WSCOL_OFF (BB * NSLICE * NN)  // 131072 floats

typedef __attribute__((ext_vector_type(8))) short bf16x8;
typedef __attribute__((ext_vector_type(16))) float f32x16;

static __device__ inline unsigned short f2bf(float f) {
    unsigned int u = __float_as_uint(f);
    return (unsigned short)((u + 0x7FFFu + ((u >> 16) & 1u)) >> 16);  // RNE
}
static __device__ inline bf16x8 bzero() {
    bf16x8 z;
    #pragma unroll
    for (int i = 0; i < 8; ++i) z[i] = 0;
    return z;
}
static __device__ inline f32x16 fzero16() {
    f32x16 z;
    #pragma unroll
    for (int i = 0; i < 16; ++i) z[i] = 0.f;
    return z;
}
static __device__ inline float min3f(float a, float b, float c) {
    return fminf(fminf(a, b), c);     // clang fuses to v_min3_f32
}
// min over 32 values (two f32x16) via min3 tree: 17 ops, depth ~4.
static __device__ inline float colmin32(const f32x16 x, const f32x16 y) {
    float e[32];
    #pragma unroll
    for (int i = 0; i < 16; ++i) { e[i] = x[i]; e[16 + i] = y[i]; }
    float p[11];
    #pragma unroll
    for (int i = 0; i < 10; ++i) p[i] = min3f(e[3*i], e[3*i+1], e[3*i+2]);
    p[10] = fminf(e[30], e[31]);
    const float q0 = min3f(p[0], p[1], p[2]);
    const float q1 = min3f(p[3], p[4], p[5]);
    const float q2 = min3f(p[6], p[7], p[8]);
    const float q3 = fminf(p[9], p[10]);
    return fminf(min3f(q0, q1, q2), q3);
}

#define MFMA32(Af, Bf, Cf) __builtin_amdgcn_mfma_f32_32x32x16_bf16(Af, Bf, Cf, 0, 0, 0)

// ---------------------------------------------------------------------------
// Chamfer pass: ONE distance matrix, BOTH reductions.
// d2 = dot_K5([-2p,p2,1],[t,1,t2]) in a single 32x32x16 MFMA.
// Rows (pred): register min3. Cols (gt): per-(wave,half) bf16 partials via
// PLAIN ds_write_u16 (no RMW atomics; every slot written once per jt),
// reduced across the 8 planes in the epilogue. B-frags prefetched 1 jt ahead.
// Grid: exactly 512 blocks (2/CU). Block 0 zeroes out.
// ---------------------------------------------------------------------------
__global__ __launch_bounds__(256, 2) void chamfer_min_kernel(
    const float* __restrict__ pred, const float* __restrict__ gt,
    float* __restrict__ ws, float* __restrict__ out)
{
    const int bx  = blockIdx.x;
    const int tid = threadIdx.x;
    if (bx == 0 && tid == 0) *out = 0.0f;

    __shared__ __align__(16) float smem[8704];            // stage 32KB | row-epi 34.8KB
    __shared__ __align__(16) unsigned short colw[8 * CSTRIDE];  // 32.5KB bf16 col planes

    const int lane = tid & 63;
    const int w    = tid >> 6;
    const int li   = lane & 31;
    const int hi   = lane >> 5;
    const int tile   = bx & 15;
    const int mslice = (bx >> 4) & 1;
    const int b      = bx >> 5;
    const float* rb = pred + (size_t)b * NN * 3;
    const float* cb = gt + ((size_t)b * MM + (size_t)mslice * SLICE_COLS) * 3;

    // A-frags (pred rows): lanes 0-31 carry k=0..7 (k0..4 used); lanes 32-63 zero.
    const int rbase = tile * ROWS_PER_BLOCK + w * 64;
    bf16x8 A0 = bzero(), A1 = bzero();
    if (lane < 32) {
        #pragma unroll
        for (int f = 0; f < 2; ++f) {
            const float* rp = rb + (size_t)(rbase + f * 32 + li) * 3;
            const float px = rp[0], py = rp[1], pz = rp[2];
            const float p2 = px * px + py * py + pz * pz;
            bf16x8 fr = bzero();
            fr[0] = (short)f2bf(-2.f * px);
            fr[1] = (short)f2bf(-2.f * py);
            fr[2] = (short)f2bf(-2.f * pz);
            fr[3] = (short)f2bf(p2);
            fr[4] = (short)0x3F80;          // 1.0
            if (f == 0) A0 = fr; else A1 = fr;
        }
    }

    // Stage gt slice: packed bf16x8 per col = (t,1,t2,0,0,0).
    uint4* sB = (uint4*)smem;
    #pragma unroll
    for (int i = 0; i < SLICE_COLS / 512; ++i) {
        const int c0 = i * 512 + 2 * tid;
        const float2* sp = (const float2*)(cb + (size_t)c0 * 3);
        const float2 v0 = sp[0], v1 = sp[1], v2 = sp[2];
        const float t2a = v0.x * v0.x + v0.y * v0.y + v1.x * v1.x;
        const float t2b = v1.y * v1.y + v2.x * v2.x + v2.y * v2.y;
        uint4 pa, pb;
        pa.x = (unsigned)f2bf(v0.x) | ((unsigned)f2bf(v0.y) << 16);
        pa.y = (unsigned)f2bf(v1.x) | (0x3F80u << 16);
        pa.z = (unsigned)f2bf(t2a);
        pa.w = 0u;
        pb.x = (unsigned)f2bf(v1.y) | ((unsigned)f2bf(v2.x) << 16);
        pb.y = (unsigned)f2bf(v2.y) | (0x3F80u << 16);
        pb.z = (unsigned)f2bf(t2b);
        pb.w = 0u;
        sB[c0]     = pa;
        sB[c0 + 1] = pb;
    }
    __syncthreads();

    float mv0[16], mv1[16];
    #pragma unroll
    for (int r = 0; r < 16; ++r) { mv0[r] = 3.4e38f; mv1[r] = 3.4e38f; }

    const f32x16 Z = fzero16();
    const bf16x8* sBf = (const bf16x8*)smem;
    unsigned short* myplane = &colw[(w * 2 + hi) * CSTRIDE];

    // Pipelined jt loop: prefetch next B-frags; 4 MFMAs; row min3; col trees
    // reduced to bf16 and plain-written to this half-wave's plane.
    bf16x8 c1 = sBf[li], c2 = sBf[32 + li];      // lanes>=32 dup-read (A=0 there)
    for (int jt = 0; jt < NJT; ++jt) {
        bf16x8 n1 = c1, n2 = c2;
        if (jt + 1 < NJT) {
            n1 = sBf[(jt + 1) * 64 + li];
            n2 = sBf[(jt + 1) * 64 + 32 + li];
        }
        f32x16 a0 = MFMA32(A0, c1, Z);
        f32x16 a1 = MFMA32(A0, c2, Z);
        f32x16 a2 = MFMA32(A1, c1, Z);
        f32x16 a3 = MFMA32(A1, c2, Z);
        #pragma unroll
        for (int r = 0; r < 16; ++r)
            mv0[r] = min3f(a0[r], a1[r], mv0[r]);
        #pragma unroll
        for (int r = 0; r < 16; ++r)
            mv1[r] = min3f(a2[r], a3[r], mv1[r]);
        myplane[jt * 64 + li]      = f2bf(colmin32(a0, a2));
        myplane[jt * 64 + 32 + li] = f2bf(colmin32(a1, a3));
        c1 = n1; c2 = n2;
    }
    __syncthreads();                              // colw complete; stage free

    // Col epilogue: reduce 8 bf16 planes -> f32, coalesced float4 ws stores.
    {
        float cm[8];
        #pragma unroll
        for (int j = 0; j < 8; ++j) cm[j] = 3.4e38f;
        #pragma unroll
        for (int p = 0; p < 8; ++p) {
            const uint4 v = *(const uint4*)&colw[p * CSTRIDE + tid * 8];
            cm[0] = fminf(cm[0], __uint_as_float(v.x << 16));
            cm[1] = fminf(cm[1], __uint_as_float(v.x & 0xFFFF0000u));
            cm[2] = fminf(cm[2], __uint_as_float(v.y << 16));
            cm[3] = fminf(cm[3], __uint_as_float(v.y & 0xFFFF0000u));
            cm[4] = fminf(cm[4], __uint_as_float(v.z << 16));
            cm[5] = fminf(cm[5], __uint_as_float(v.z & 0xFFFF0000u));
            cm[6] = fminf(cm[6], __uint_as_float(v.w << 16));
            cm[7] = fminf(cm[7], __uint_as_float(v.w & 0xFFFF0000u));
        }
        float* wc = ws + WSCOL_OFF
                  + (((size_t)b * 16 + tile) * NSLICE + mslice) * SLICE_COLS;
        *(float4*)&wc[tid * 8]     = make_float4(cm[0], cm[1], cm[2], cm[3]);
        *(float4*)&wc[tid * 8 + 4] = make_float4(cm[4], cm[5], cm[6], cm[7]);
    }

    // Row epilogue: transpose partial mins via LDS [li][row], stride 68.
    {
        float* wb = smem + w * EPW + li * 68;
        #pragma unroll
        for (int q = 0; q < 4; ++q) {
            const int rl = q * 8 + hi * 4;
            *(float4*)&wb[rl]      = make_float4(mv0[4*q], mv0[4*q+1], mv0[4*q+2], mv0[4*q+3]);
            *(float4*)&wb[rl + 32] = make_float4(mv1[4*q], mv1[4*q+1], mv1[4*q+2], mv1[4*q+3]);
        }
    }
    __syncthreads();
    {
        const int wsrc = tid >> 6, rl = tid & 63;
        const float* rb2 = smem + wsrc * EPW + rl;
        float m = 3.4e38f;
        #pragma unroll
        for (int c = 0; c < 32; c += 2) m = min3f(rb2[c * 68], rb2[(c + 1) * 68], m);
        ws[((size_t)b * NSLICE + mslice) * NN + tile * ROWS_PER_BLOCK + tid] = m;
    }
}

// ---------------------------------------------------------------------------
// Finish (+reg), 48 blocks:
//   [0,16):  rows for b   — min over 2 slices, sqrt, sum (coalesced).
//   [16,32): cols for b   — min over 32 (tile,slice) planes, sqrt, sum
//            (fully coalesced float4 reads; fixes the 16KB-stride reads).
//   [32,48): regularizer via MFMA.
// ---------------------------------------------------------------------------
__global__ __launch_bounds__(256) void finish_reg_kernel(
    const float* __restrict__ ws, const float* __restrict__ trans,
    float* __restrict__ out)
{
    const int bx  = blockIdx.x;
    const int tid = threadIdx.x;
    __shared__ float ssum[4];

    if (bx < BB) {
        // ------------------------ pred rows ------------------------
        const int b = bx;
        const float* p0 = ws + ((size_t)b * NSLICE) * NN;
        float s = 0.f;
        #pragma unroll 4
        for (int i = 0; i < NN / 256; ++i) {
            const int n = i * 256 + tid;
            const float v = fminf(p0[n], p0[NN + n]);
            s += sqrtf(fmaxf(v, 0.0f));
        }
        #pragma unroll
        for (int off = 32; off > 0; off >>= 1)
            s += __shfl_down(s, off, 64);
        if ((tid & 63) == 0) ssum[tid >> 6] = s;
        __syncthreads();
        if (tid == 0)
            atomicAdd(out, (ssum[0] + ssum[1] + ssum[2] + ssum[3])
                               * (1.0f / ((float)BB * (float)NN)));
        return;
    }
    if (bx < 2 * BB) {
        // ------------------------- gt cols -------------------------
        const int b = bx - BB;
        const float* base = ws + WSCOL_OFF + (size_t)b * 16 * NSLICE * SLICE_COLS;
        float acc[8];
        #pragma unroll
        for (int j = 0; j < 8; ++j) acc[j] = 3.4e38f;
        #pragma unroll 4
        for (int p = 0; p < 16 * NSLICE; ++p) {
            const float* pl = base + (size_t)p * SLICE_COLS + tid * 8;
            const float4 x = *(const float4*)pl;
            const float4 y = *(const float4*)(pl + 4);
            acc[0] = fminf(acc[0], x.x); acc[1] = fminf(acc[1], x.y);
            acc[2] = fminf(acc[2], x.z); acc[3] = fminf(acc[3], x.w);
            acc[4] = fminf(acc[4], y.x); acc[5] = fminf(acc[5], y.y);
            acc[6] = fminf(acc[6], y.z); acc[7] = fminf(acc[7], y.w);
        }
        float s = 0.f;
        #pragma unroll
        for (int j = 0; j < 8; ++j) s += sqrtf(fmaxf(acc[j], 0.0f));
        #pragma unroll
        for (int off = 32; off > 0; off >>= 1)
            s += __shfl_down(s, off, 64);
        if ((tid & 63) == 0) ssum[tid >> 6] = s;
        __syncthreads();
        if (tid == 0)
            atomicAdd(out, (ssum[0] + ssum[1] + ssum[2] + ssum[3])
                               * (1.0f / ((float)BB * (float)NN)));
        return;
    }

    // ------------------------- regularizer -------------------------
    if (tid < 64) {
        const int b = bx - 2 * BB;
        const int lane = tid;
        const int hi = lane >> 5, li = lane & 31;
        const float* T = trans + (size_t)b * 64 * 64;
        bf16x8 frag[2][4];
        #pragma unroll
        for (int h = 0; h < 2; ++h)
            #pragma unroll
            for (int s = 0; s < 4; ++s) {
                const float* rp = T + (size_t)(h * 32 + li) * 64 + s * 16 + hi * 8;
                const float4 u0 = *(const float4*)rp;
                const float4 u1 = *(const float4*)(rp + 4);
                bf16x8 fr;
                fr[0] = (short)f2bf(u0.x); fr[1] = (short)f2bf(u0.y);
                fr[2] = (short)f2bf(u0.z); fr[3] = (short)f2bf(u0.w);
                fr[4] = (short)f2bf(u1.x); fr[5] = (short)f2bf(u1.y);
                fr[6] = (short)f2bf(u1.z); fr[7] = (short)f2bf(u1.w);
                frag[h][s] = fr;
            }
        float fsum = 0.f;
        #pragma unroll
        for (int fi = 0; fi < 2; ++fi)
            #pragma unroll
            for (int fj = 0; fj < 2; ++fj) {
                f32x16 a = fzero16();
                #pragma unroll
                for (int s = 0; s < 4; ++s)
                    a = MFMA32(frag[fi][s], frag[fj][s], a);
                #pragma unroll
                for (int r = 0; r < 16; ++r) {
                    const int row = fi * 32 + (r & 3) + 8 * (r >> 2) + 4 * hi;
                    const int col = fj * 32 + li;
                    const float d = a[r] - ((row == col) ? 1.0f : 0.0f);
                    fsum = fmaf(d, d, fsum);
                }
            }
        #pragma unroll
        for (int off = 32; off > 0; off >>= 1)
            fsum += __shfl_down(fsum, off, 64);
        if (lane == 0)
            atomicAdd(out, (0.1f / (float)BB) * sqrtf(fsum));
    }
}

extern "C" void kernel_launch(void* const* d_in, const int* in_sizes, int n_in,
                              void* d_out, int out_size, void* d_ws, size_t ws_size,
                              hipStream_t stream)
{
    const float* pred  = (const float*)d_in[0];
    const float* gt    = (const float*)d_in[1];
    const float* trans = (const float*)d_in[2];
    float* out = (float*)d_out;
    float* ws = (float*)d_ws;

    chamfer_min_kernel<<<dim3(NCHAMFER), dim3(256), 0, stream>>>(pred, gt, ws, out);
    finish_reg_kernel<<<dim3(3 * BB), dim3(256), 0, stream>>>(ws, trans, out);
}

// Round 13
// 27.084 us; speedup vs baseline: 1.6152x; 1.0311x over previous
//
#include <hip/hip_runtime.h>
#include <math.h>

// Problem constants: B=16, N=M=4096, K=64.
#define BB 16
#define NN 4096
#define MM 4096
#define NSLICE 2
#define SLICE_COLS 2048               // cols per block
#define NJT (SLICE_COLS / 64)         // 32
#define ROWS_PER_BLOCK 256            // 8 waves x 32 rows
#define NCHAMFER 512                  // 16 tiles * 2 slices * 16 b
#define WSCOL_OFF (BB * NSLICE * NN)  // 131072 floats; then u32 col planes

typedef __attribute__((ext_vector_type(8))) short bf16x8;
typedef __attribute__((ext_vector_type(16))) float f32x16;

static __device__ inline unsigned short f2bf(float f) {
    unsigned int u = __float_as_uint(f);
    return (unsigned short)((u + 0x7FFFu + ((u >> 16) & 1u)) >> 16);  // RNE
}
static __device__ inline bf16x8 bzero() {
    bf16x8 z;
    #pragma unroll
    for (int i = 0; i < 8; ++i) z[i] = 0;
    return z;
}
static __device__ inline f32x16 fzero16() {
    f32x16 z;
    #pragma unroll
    for (int i = 0; i < 16; ++i) z[i] = 0.f;
    return z;
}
static __device__ inline float min3f(float a, float b, float c) {
    return fminf(fminf(a, b), c);     // v_min3_f32
}
// min over one f32x16 via min3 tree: 8 ops.
static __device__ inline float tree16(const f32x16 x) {
    const float p0 = min3f(x[0], x[1], x[2]);
    const float p1 = min3f(x[3], x[4], x[5]);
    const float p2 = min3f(x[6], x[7], x[8]);
    const float p3 = min3f(x[9], x[10], x[11]);
    const float p4 = min3f(x[12], x[13], x[14]);
    const float q0 = min3f(p0, p1, x[15]);
    const float q1 = min3f(p2, p3, p4);
    return fminf(q0, q1);
}

#define MFMA32(Af, Bf, Cf) __builtin_amdgcn_mfma_f32_32x32x16_bf16(Af, Bf, Cf, 0, 0, 0)

// ---------------------------------------------------------------------------
// Chamfer: ONE distance matrix, BOTH reductions; occupancy-first shape.
// 512-thread blocks, 8 waves x 1 A-frag (32 rows) => ~90 VGPR/wave -> a true
// 4 waves/SIMD (16 waves/CU). Per jt: 2 MFMA, 16 row-min3, 2 tree16 +
// shfl_xor(32) combine, 1 cvt_pk_bf16 + 1 u32 plane write. Col partials in
// 8 per-wave bf16-pair planes (plain writes); rows in regs.
// LDS union 64KB: stage 32KB + colw 32KB | row-epi 36KB. 2 blocks/CU.
// ---------------------------------------------------------------------------
__global__ __launch_bounds__(512, 4) void chamfer_min_kernel(
    const float* __restrict__ pred, const float* __restrict__ gt,
    float* __restrict__ ws, float* __restrict__ out)
{
    const int bx  = blockIdx.x;
    const int tid = threadIdx.x;
    if (bx == 0 && tid == 0) *out = 0.0f;

    __shared__ __align__(16) unsigned char lds[65536];
    uint4* sB = (uint4*)lds;                          // [0, 32768)
    const bf16x8* sBf = (const bf16x8*)lds;
    unsigned* colw = (unsigned*)(lds + 32768);        // [32768, 65536): 8 x 1024 u32
    float* epi = (float*)lds;                         // row-epi reuse [0, 36864)

    const int lane = tid & 63;
    const int w    = tid >> 6;                        // wave 0..7
    const int li   = lane & 31;
    const int hi   = lane >> 5;
    const int tile   = bx & 15;
    const int mslice = (bx >> 4) & 1;
    const int b      = bx >> 5;
    const float* rb = pred + (size_t)b * NN * 3;
    const float* cb = gt + ((size_t)b * MM + (size_t)mslice * SLICE_COLS) * 3;

    // A-frag: 32 rows (rbase+li). Lanes 0-31 carry k=0..7 (k0..4); 32-63 zero.
    const int rbase = tile * ROWS_PER_BLOCK + w * 32;
    bf16x8 A0 = bzero();
    if (lane < 32) {
        const float* rp = rb + (size_t)(rbase + li) * 3;
        const float px = rp[0], py = rp[1], pz = rp[2];
        const float p2 = px * px + py * py + pz * pz;
        bf16x8 fr = bzero();
        fr[0] = (short)f2bf(-2.f * px);
        fr[1] = (short)f2bf(-2.f * py);
        fr[2] = (short)f2bf(-2.f * pz);
        fr[3] = (short)f2bf(p2);
        fr[4] = (short)0x3F80;              // 1.0
        A0 = fr;
    }

    // Stage gt slice: packed bf16x8 per col = (t,1,t2,0,0,0). 2 col-pairs/thread.
    #pragma unroll
    for (int i = 0; i < 2; ++i) {
        const int c0 = (i * 512 + tid) * 2;
        const float2* sp = (const float2*)(cb + (size_t)c0 * 3);
        const float2 v0 = sp[0], v1 = sp[1], v2 = sp[2];
        const float t2a = v0.x * v0.x + v0.y * v0.y + v1.x * v1.x;
        const float t2b = v1.y * v1.y + v2.x * v2.x + v2.y * v2.y;
        uint4 pa, pb;
        pa.x = (unsigned)f2bf(v0.x) | ((unsigned)f2bf(v0.y) << 16);
        pa.y = (unsigned)f2bf(v1.x) | (0x3F80u << 16);
        pa.z = (unsigned)f2bf(t2a);
        pa.w = 0u;
        pb.x = (unsigned)f2bf(v1.y) | ((unsigned)f2bf(v2.x) << 16);
        pb.y = (unsigned)f2bf(v2.y) | (0x3F80u << 16);
        pb.z = (unsigned)f2bf(t2b);
        pb.w = 0u;
        sB[c0]     = pa;
        sB[c0 + 1] = pb;
    }
    __syncthreads();

    float mv[16];
    #pragma unroll
    for (int r = 0; r < 16; ++r) mv[r] = 3.4e38f;

    const f32x16 Z = fzero16();
    unsigned* myplane = colw + w * 1024;

    bf16x8 c1 = sBf[li], c2 = sBf[32 + li];   // lanes>=32 dup-read (A=0 there)
    #pragma unroll 2
    for (int jt = 0; jt < NJT; ++jt) {
        bf16x8 n1 = c1, n2 = c2;
        if (jt + 1 < NJT) {
            n1 = sBf[(jt + 1) * 64 + li];
            n2 = sBf[(jt + 1) * 64 + 32 + li];
        }
        f32x16 a0 = MFMA32(A0, c1, Z);        // col group li
        f32x16 a1 = MFMA32(A0, c2, Z);        // col group 32+li
        // row mins: each acc row over both col groups
        #pragma unroll
        for (int r = 0; r < 16; ++r)
            mv[r] = min3f(a0[r], a1[r], mv[r]);
        // col partials: 16-row tree, combine across hi halves, pack bf16 pair
        float tA = tree16(a0);
        float tB = tree16(a1);
        tA = fminf(tA, __shfl_xor(tA, 32, 64));
        tB = fminf(tB, __shfl_xor(tB, 32, 64));
        unsigned pk;
        asm("v_cvt_pk_bf16_f32 %0, %1, %2" : "=v"(pk) : "v"(tA), "v"(tB));
        if (lane < 32) myplane[jt * 32 + li] = pk;
        c1 = n1; c2 = n2;
    }
    __syncthreads();                          // colw complete

    // Col epilogue: umin across 8 planes per u16 half (bf16>=0 => bit order),
    // repack, coalesced u32 store to ws col planes.
    {
        unsigned* wc = (unsigned*)(ws + WSCOL_OFF)
                     + (((size_t)b * 16 + tile) * NSLICE + mslice) * 1024;
        #pragma unroll
        for (int i = 0; i < 2; ++i) {
            const int slot = i * 512 + tid;
            unsigned la = 0xFFFFu, ha = 0xFFFFu;
            #pragma unroll
            for (int p = 0; p < 8; ++p) {
                const unsigned u = colw[p * 1024 + slot];
                la = min(la, u & 0xFFFFu);
                ha = min(ha, u >> 16);
            }
            wc[slot] = la | (ha << 16);
        }
    }
    __syncthreads();                          // colw free; row transpose begins

    // Row epilogue: transpose mv via LDS [wave][li][row_local], stride 36.
    {
        float* wb = epi + w * 1152 + li * 36;
        #pragma unroll
        for (int q = 0; q < 4; ++q)
            *(float4*)&wb[q * 8 + hi * 4] =
                make_float4(mv[4*q], mv[4*q+1], mv[4*q+2], mv[4*q+3]);
    }
    __syncthreads();

    if (tid < ROWS_PER_BLOCK) {
        const int wsrc = tid >> 5, rl = tid & 31;
        const float* rr = epi + wsrc * 1152 + rl;
        float m = 3.4e38f;
        #pragma unroll
        for (int c = 0; c < 32; c += 2) m = min3f(rr[c * 36], rr[(c + 1) * 36], m);
        ws[((size_t)b * NSLICE + mslice) * NN + tile * ROWS_PER_BLOCK + tid] = m;
    }
}

// ---------------------------------------------------------------------------
// Finish (+reg), 48 blocks:
//   [0,16):  rows for b — min over 2 slices, sqrt, sum.
//   [16,32): cols for b — u16-min over 16 tile planes, decode bf16, sqrt, sum.
//   [32,48): regularizer via MFMA.
// ---------------------------------------------------------------------------
__global__ __launch_bounds__(256) void finish_reg_kernel(
    const float* __restrict__ ws, const float* __restrict__ trans,
    float* __restrict__ out)
{
    const int bx  = blockIdx.x;
    const int tid = threadIdx.x;
    __shared__ float ssum[4];

    if (bx < BB) {
        // ------------------------ pred rows ------------------------
        const int b = bx;
        const float* p0 = ws + ((size_t)b * NSLICE) * NN;
        float s = 0.f;
        #pragma unroll 4
        for (int i = 0; i < NN / 256; ++i) {
            const int n = i * 256 + tid;
            const float v = fminf(p0[n], p0[NN + n]);
            s += sqrtf(fmaxf(v, 0.0f));
        }
        #pragma unroll
        for (int off = 32; off > 0; off >>= 1)
            s += __shfl_down(s, off, 64);
        if ((tid & 63) == 0) ssum[tid >> 6] = s;
        __syncthreads();
        if (tid == 0)
            atomicAdd(out, (ssum[0] + ssum[1] + ssum[2] + ssum[3])
                               * (1.0f / ((float)BB * (float)NN)));
        return;
    }
    if (bx < 2 * BB) {
        // ------------------------- gt cols -------------------------
        const int b = bx - BB;
        const unsigned* base = (const unsigned*)(ws + WSCOL_OFF)
                             + (size_t)b * 16 * NSLICE * 1024;
        float s = 0.f;
        #pragma unroll
        for (int i = 0; i < 8; ++i) {
            const int idx = i * 256 + tid;          // 0..2047
            const int sl  = idx >> 10;              // slice
            const int slot = idx & 1023;
            unsigned la = 0xFFFFu, ha = 0xFFFFu;
            #pragma unroll
            for (int t = 0; t < 16; ++t) {
                const unsigned u = base[((size_t)t * NSLICE + sl) * 1024 + slot];
                la = min(la, u & 0xFFFFu);
                ha = min(ha, u >> 16);
            }
            s += sqrtf(fmaxf(__uint_as_float(la << 16), 0.0f));
            s += sqrtf(fmaxf(__uint_as_float(ha << 16), 0.0f));
        }
        #pragma unroll
        for (int off = 32; off > 0; off >>= 1)
            s += __shfl_down(s, off, 64);
        if ((tid & 63) == 0) ssum[tid >> 6] = s;
        __syncthreads();
        if (tid == 0)
            atomicAdd(out, (ssum[0] + ssum[1] + ssum[2] + ssum[3])
                               * (1.0f / ((float)BB * (float)NN)));
        return;
    }

    // ------------------------- regularizer -------------------------
    if (tid < 64) {
        const int b = bx - 2 * BB;
        const int lane = tid;
        const int hi = lane >> 5, li = lane & 31;
        const float* T = trans + (size_t)b * 64 * 64;
        bf16x8 frag[2][4];
        #pragma unroll
        for (int h = 0; h < 2; ++h)
            #pragma unroll
            for (int s = 0; s < 4; ++s) {
                const float* rp = T + (size_t)(h * 32 + li) * 64 + s * 16 + hi * 8;
                const float4 u0 = *(const float4*)rp;
                const float4 u1 = *(const float4*)(rp + 4);
                bf16x8 fr;
                fr[0] = (short)f2bf(u0.x); fr[1] = (short)f2bf(u0.y);
                fr[2] = (short)f2bf(u0.z); fr[3] = (short)f2bf(u0.w);
                fr[4] = (short)f2bf(u1.x); fr[5] = (short)f2bf(u1.y);
                fr[6] = (short)f2bf(u1.z); fr[7] = (short)f2bf(u1.w);
                frag[h][s] = fr;
            }
        float fsum = 0.f;
        #pragma unroll
        for (int fi = 0; fi < 2; ++fi)
            #pragma unroll
            for (int fj = 0; fj < 2; ++fj) {
                f32x16 a = fzero16();
                #pragma unroll
                for (int s = 0; s < 4; ++s)
                    a = MFMA32(frag[fi][s], frag[fj][s], a);
                #pragma unroll
                for (int r = 0; r < 16; ++r) {
                    const int row = fi * 32 + (r & 3) + 8 * (r >> 2) + 4 * hi;
                    const int col = fj * 32 + li;
                    const float d = a[r] - ((row == col) ? 1.0f : 0.0f);
                    fsum = fmaf(d, d, fsum);
                }
            }
        #pragma unroll
        for (int off = 32; off > 0; off >>= 1)
            fsum += __shfl_down(fsum, off, 64);
        if (lane == 0)
            atomicAdd(out, (0.1f / (float)BB) * sqrtf(fsum));
    }
}

extern "C" void kernel_launch(void* const* d_in, const int* in_sizes, int n_in,
                              void* d_out, int out_size, void* d_ws, size_t ws_size,
                              hipStream_t stream)
{
    const float* pred  = (const float*)d_in[0];
    const float* gt    = (const float*)d_in[1];
    const float* trans = (const float*)d_in[2];
    float* out = (float*)d_out;
    float* ws = (float*)d_ws;

    chamfer_min_kernel<<<dim3(NCHAMFER), dim3(512), 0, stream>>>(pred, gt, ws, out);
    finish_reg_kernel<<<dim3(3 * BB), dim3(256), 0, stream>>>(ws, trans, out);
}